// Round 4
// baseline (333.653 us; speedup 1.0000x reference)
//
#include <hip/hip_runtime.h>
#include <math.h>

#define IMG 512
#define PLANES 96            // 32 N * 3 C
#define XS_W 54              // valid output columns per wave (64 lanes - 10 halo)
#define NXS 10               // ceil(512/54)
#define YS_H 128             // output rows per wave (halo amortization: 138 steps/128 rows)
#define NYS 4                // 512/128
#define WPB 4                // waves per block
#define NBLK ((PLANES * NXS * NYS) / WPB)   // 960 blocks
#define INV_NPIX (1.0 / 25165824.0)

// ws layout: float4 part[NBLK] (15360 B) — per-block partial sums, plain stores.

static __device__ __forceinline__ float rfl(float x) {
    return __int_as_float(__builtin_amdgcn_readfirstlane(__float_as_int(x)));
}

// ---- DPP wave-wide lane shifts (VALU pipe — keeps the per-CU DS crossbar idle).
// wave_shr:1 (0x138): lane i reads lane i-1. wave_shl:1 (0x130): lane i reads lane i+1.
// Boundary lanes get 0 (bound_ctrl) — only ever consumed by non-emitted halo lanes.
static __device__ __forceinline__ float dpp_shr1(float x) {
    return __int_as_float(__builtin_amdgcn_mov_dpp(__float_as_int(x), 0x138, 0xF, 0xF, true));
}
static __device__ __forceinline__ float dpp_shl1(float x) {
    return __int_as_float(__builtin_amdgcn_mov_dpp(__float_as_int(x), 0x130, 0xF, 0xF, true));
}

// One row step. Ring: 11 slots; at step t (phase P=t%11) the vertical loop
// writes each slot exactly once: slot (P+j+1)%11 gets tap weight g[10-j].
// j==10 targets slot P (emitted at step t-1) — overwritten with mul, no zeroing.
template<int P>
__device__ __forceinline__ void row_step(
    int T, int y0, bool col_ok,
    const float* __restrict__ p1, const float* __restrict__ p2,
    float& x1, float& x2, const float (&g)[11],
    float (&A)[5][11], bool out_ok, float& sL, float& sC, float& sS)
{
    const int t = T + P;
    // ---- prefetch row t+1 (coalesced: lane = column) ----
    const int gy_next = y0 - 4 + t;
    float nx1 = 0.f, nx2 = 0.f;
    if (col_ok && (unsigned)gy_next < IMG) {
        int off = gy_next * IMG;
        nx1 = p1[off];
        nx2 = p2[off];
    }
    // ---- horizontal window via DPP wave shifts (4 independent chains) ----
    float a[11], b[11];
    a[5] = x1; b[5] = x2;
    a[4] = dpp_shr1(x1);   b[4] = dpp_shr1(x2);
    a[6] = dpp_shl1(x1);   b[6] = dpp_shl1(x2);
    a[3] = dpp_shr1(a[4]); b[3] = dpp_shr1(b[4]);
    a[7] = dpp_shl1(a[6]); b[7] = dpp_shl1(b[6]);
    a[2] = dpp_shr1(a[3]); b[2] = dpp_shr1(b[3]);
    a[8] = dpp_shl1(a[7]); b[8] = dpp_shl1(b[7]);
    a[1] = dpp_shr1(a[2]); b[1] = dpp_shr1(b[2]);
    a[9] = dpp_shl1(a[8]); b[9] = dpp_shl1(b[8]);
    a[0] = dpp_shr1(a[1]); b[0] = dpp_shr1(b[1]);
    a[10] = dpp_shl1(a[9]); b[10] = dpp_shl1(b[9]);
    // ---- horizontal 11-tap for 5 quantities (weights in SGPRs) ----
    float t1 = g[0] * a[0], t2 = g[0] * b[0];
    float H1 = t1, H2 = t2;
    float H11 = t1 * a[0], H22 = t2 * b[0], H12 = t1 * b[0];
    #pragma unroll
    for (int j = 1; j < 11; ++j) {
        float w = g[j];
        t1 = w * a[j]; t2 = w * b[j];
        H1 += t1; H2 += t2;
        H11 = fmaf(t1, a[j], H11);
        H22 = fmaf(t2, b[j], H22);
        H12 = fmaf(t1, b[j], H12);
    }
    // ---- vertical accumulate into ring: H_t -> output r=t-10+j, weight g[10-j],
    //      slot (P+j+1)%11 ; statically indexed since t ≡ P (mod 11) ----
    #pragma unroll
    for (int j = 0; j < 11; ++j) {
        const int s = (P + j + 1) % 11;
        float w = g[10 - j];
        if (j == 10) {                             // fresh slot (== P): overwrite
            A[0][s] = w * H1;
            A[1][s] = w * H2;
            A[2][s] = w * H11;
            A[3][s] = w * H22;
            A[4][s] = w * H12;
        } else {
            A[0][s] = fmaf(w, H1,  A[0][s]);
            A[1][s] = fmaf(w, H2,  A[1][s]);
            A[2][s] = fmaf(w, H11, A[2][s]);
            A[3][s] = fmaf(w, H22, A[3][s]);
            A[4][s] = fmaf(w, H12, A[4][s]);
        }
    }
    // ---- emit output row r = t-10 (slot (P+1)%11) ----
    const int es = (P + 1) % 11;
    if (t >= 10) {                                 // wave-uniform branch (t <= 137 always)
        float mu1 = A[0][es], mu2 = A[1][es];
        float x11 = A[2][es], x22 = A[3][es], x12 = A[4][es];
        float mu1s = mu1 * mu1, mu2s = mu2 * mu2, mu12 = mu1 * mu2;
        float v1 = x11 - mu1s, v2 = x22 - mu2s, v12 = x12 - mu12;
        float a1 = fabsf(v1), a2 = fabsf(v2);
        float q12 = sqrtf(a1 * a2);                // sqrt(a1)*sqrt(a2)
        const float C1 = 1e-4f, C2 = 9e-4f, C3 = 4.5e-4f;
        float eL = __fdividef(2.f * mu12 + C1, mu1s + mu2s + C1);
        float eC = __fdividef(2.f * q12 + C2, a1 + a2 + C2);
        float eS = __fdividef(v12 + C3, q12 + C3);
        if (out_ok) { sL += eL; sC += eC; sS += eS; }
    }
    x1 = nx1; x2 = nx2;
}

__global__ __launch_bounds__(256, 4) void ssim_main(
    const float* __restrict__ img1, const float* __restrict__ img2,
    const float* __restrict__ win, float4* __restrict__ part)
{
    const int lane = threadIdx.x & 63;
    const int widx = threadIdx.x >> 6;
    const int wid  = blockIdx.x * WPB + widx;
    const int plane = wid / (NXS * NYS);
    const int rem   = wid % (NXS * NYS);
    const int ys = rem / NXS, xs = rem % NXS;
    const int x0 = xs * XS_W;
    const int y0 = ys * YS_H;
    const int col = x0 - 5 + lane;                 // this lane's image column
    const bool col_ok = (unsigned)col < IMG;
    const bool out_ok = (lane >= 5) && (lane <= 58) && col_ok;

    // separable 1-D Gaussian from diagonal of 2-D window (channel 0):
    // w2d[i][i] = g[i]^2 -> g[i] = sqrt(win[i*12]). Uniform -> SGPRs.
    float g[11];
    #pragma unroll
    for (int j = 0; j < 11; ++j) g[j] = rfl(sqrtf(win[j * 12]));

    const float* p1 = img1 + (size_t)plane * (IMG * IMG) + col;
    const float* p2 = img2 + (size_t)plane * (IMG * IMG) + col;

    // load row t=0 (gy = y0-5)
    float x1 = 0.f, x2 = 0.f;
    {
        int gy = y0 - 5;
        if (col_ok && (unsigned)gy < IMG) { x1 = p1[gy * IMG]; x2 = p2[gy * IMG]; }
    }

    float A[5][11];
    #pragma unroll
    for (int q = 0; q < 5; ++q)
        #pragma unroll
        for (int s = 0; s < 11; ++s) A[q][s] = 0.f;

    float sL = 0.f, sC = 0.f, sS = 0.f;

    #pragma unroll 1
    for (int T = 0; T < 132; T += 11) {            // t = 0..131
        row_step<0>(T, y0, col_ok, p1, p2, x1, x2, g, A, out_ok, sL, sC, sS);
        row_step<1>(T, y0, col_ok, p1, p2, x1, x2, g, A, out_ok, sL, sC, sS);
        row_step<2>(T, y0, col_ok, p1, p2, x1, x2, g, A, out_ok, sL, sC, sS);
        row_step<3>(T, y0, col_ok, p1, p2, x1, x2, g, A, out_ok, sL, sC, sS);
        row_step<4>(T, y0, col_ok, p1, p2, x1, x2, g, A, out_ok, sL, sC, sS);
        row_step<5>(T, y0, col_ok, p1, p2, x1, x2, g, A, out_ok, sL, sC, sS);
        row_step<6>(T, y0, col_ok, p1, p2, x1, x2, g, A, out_ok, sL, sC, sS);
        row_step<7>(T, y0, col_ok, p1, p2, x1, x2, g, A, out_ok, sL, sC, sS);
        row_step<8>(T, y0, col_ok, p1, p2, x1, x2, g, A, out_ok, sL, sC, sS);
        row_step<9>(T, y0, col_ok, p1, p2, x1, x2, g, A, out_ok, sL, sC, sS);
        row_step<10>(T, y0, col_ok, p1, p2, x1, x2, g, A, out_ok, sL, sC, sS);
    }
    // tail: t = 132..137 (132 % 11 == 0, phases 0..5)
    row_step<0>(132, y0, col_ok, p1, p2, x1, x2, g, A, out_ok, sL, sC, sS);
    row_step<1>(132, y0, col_ok, p1, p2, x1, x2, g, A, out_ok, sL, sC, sS);
    row_step<2>(132, y0, col_ok, p1, p2, x1, x2, g, A, out_ok, sL, sC, sS);
    row_step<3>(132, y0, col_ok, p1, p2, x1, x2, g, A, out_ok, sL, sC, sS);
    row_step<4>(132, y0, col_ok, p1, p2, x1, x2, g, A, out_ok, sL, sC, sS);
    row_step<5>(132, y0, col_ok, p1, p2, x1, x2, g, A, out_ok, sL, sC, sS);

    // ---- wave reduction, then block reduction via tiny LDS, one plain store ----
    #pragma unroll
    for (int off = 32; off > 0; off >>= 1) {
        sL += __shfl_down(sL, off, 64);
        sC += __shfl_down(sC, off, 64);
        sS += __shfl_down(sS, off, 64);
    }
    __shared__ float red[WPB][4];
    if (lane == 0) { red[widx][0] = sL; red[widx][1] = sC; red[widx][2] = sS; }
    __syncthreads();
    if (threadIdx.x == 0) {
        float L = 0.f, C = 0.f, S = 0.f;
        #pragma unroll
        for (int w = 0; w < WPB; ++w) { L += red[w][0]; C += red[w][1]; S += red[w][2]; }
        part[blockIdx.x] = make_float4(L, C, S, 0.f);
    }
}

__global__ void ssim_fin(const float4* __restrict__ part, float* __restrict__ out) {
    const int t = threadIdx.x;
    double L = 0.0, C = 0.0, S = 0.0;
    for (int i = t; i < NBLK; i += 256) {
        float4 p = part[i];
        L += (double)p.x; C += (double)p.y; S += (double)p.z;
    }
    __shared__ double red[256][3];
    red[t][0] = L; red[t][1] = C; red[t][2] = S;
    __syncthreads();
    for (int s = 128; s > 0; s >>= 1) {
        if (t < s) {
            red[t][0] += red[t + s][0];
            red[t][1] += red[t + s][1];
            red[t][2] += red[t + s][2];
        }
        __syncthreads();
    }
    if (t < 3) out[t] = (float)(red[0][t] * INV_NPIX);
}

extern "C" void kernel_launch(void* const* d_in, const int* in_sizes, int n_in,
                              void* d_out, int out_size, void* d_ws, size_t ws_size,
                              hipStream_t stream) {
    const float* img1 = (const float*)d_in[0];
    const float* img2 = (const float*)d_in[1];
    const float* win  = (const float*)d_in[2];
    float* out = (float*)d_out;
    float4* part = (float4*)d_ws;                  // NBLK * 16 B = 15360 B

    ssim_main<<<NBLK, 64 * WPB, 0, stream>>>(img1, img2, win, part);
    ssim_fin<<<1, 256, 0, stream>>>(part, out);
}